// Round 1
// baseline (307.548 us; speedup 1.0000x reference)
//
#include <hip/hip_runtime.h>
#include <math.h>

#define NPTS    131072
#define FEAT    64
#define KCLUS   2048
#define CHUNKC  256      // clusters staged per LDS chunk
#define NCHUNK  (KCLUS / CHUNKC)   // 8
#define PPW     64       // points per wave (4 MFMA row-tiles) -- was 32
#define WPB     4        // waves per 256-thread block (wave = 64 on CDNA!)
#define PPB     (PPW * WPB)   // 256 points per block
#define CANDC   20       // per-lane register candidate slots (rows/lane doubled -> 10->20)

typedef __attribute__((ext_vector_type(8))) short frag_ab;   // 8 bf16
typedef __attribute__((ext_vector_type(4))) float frag_cd;   // 4 fp32 acc

// fp32 -> bf16 RNE
__device__ __forceinline__ short f2bf(float f) {
    unsigned u = __float_as_uint(f);
    u += 0x7FFFu + ((u >> 16) & 1u);
    return (short)(u >> 16);
}

// Exact fp32 distance term (cn - 2 x.c): IDENTICAL single-chain FMA order to
// rounds 1-3/7/9/10 (matches numpy argmin on this data, absmax 0 x7).
__device__ __forceinline__ float exact_dist(const float* __restrict__ x,
                                            const float* __restrict__ c,
                                            float cnv, int p, int kk) {
    const float4* xr4 = (const float4*)&x[(size_t)p * FEAT];
    const float4* cr4 = (const float4*)&c[(size_t)kk * FEAT];
    float s = 0.f;
#pragma unroll
    for (int j = 0; j < 16; ++j) {
        float4 a4 = xr4[j], b4 = cr4[j];
        s = fmaf(a4.x, b4.x, s); s = fmaf(a4.y, b4.y, s);
        s = fmaf(a4.z, b4.z, s); s = fmaf(a4.w, b4.w, s);
    }
    return fmaf(-2.f, s, cnv);
}

// ---------------------------------------------------------------------------
// cprep: exact fp32 cnorm, cbs_t = bf16(-2c) part-major [part=f/8][k][8]
// (proven conflict-free + correct B layout), cmax = max||c||.  UNCHANGED.
// ---------------------------------------------------------------------------
__global__ void cprep_kernel(const float* __restrict__ c, float* __restrict__ cnorm,
                             short* __restrict__ cbs_t, float* __restrict__ cmax) {
    int k = blockIdx.x * blockDim.x + threadIdx.x;
    if (k >= KCLUS) return;
    const float4* row = (const float4*)&c[k * FEAT];
    float s = 0.f;
#pragma unroll
    for (int j = 0; j < 16; ++j) {
        float4 v = row[j];
        s = fmaf(v.x, v.x, s); s = fmaf(v.y, v.y, s);
        s = fmaf(v.z, v.z, s); s = fmaf(v.w, v.w, s);
        short4 b;
        b.x = f2bf(-2.f * v.x); b.y = f2bf(-2.f * v.y);
        b.z = f2bf(-2.f * v.z); b.w = f2bf(-2.f * v.w);
        *(short4*)&cbs_t[((size_t)(j >> 1) * KCLUS + k) * 8 + (j & 1) * 4] = b;
    }
    cnorm[k] = s;
    atomicMax((int*)cmax, __float_as_int(sqrtf(s)));  // positive: int-max == float-max
}

// ---------------------------------------------------------------------------
// Async-stage one 256-cluster chunk (32 KB, part-major, byte-identical layout
// to the proven csh) via global_load_lds width=16: 8 issues/wave, linear LDS
// dest (seg*1024 + lane*16), per-lane global src.  No VGPR round-trip, no
// ds_write traffic.  Entry e in [0,2048): part=e>>8, cluster=e&255.
// ---------------------------------------------------------------------------
__device__ __forceinline__ void stage_chunk(const short* __restrict__ cbs_t,
                                            short* dst, int k0, int wv, int lane) {
#pragma unroll
    for (int j = 0; j < 8; ++j) {
        const int e = (wv * 8 + j) * 64 + lane;
        const int p = e >> 8, cc = e & 255;
        const short* g = &cbs_t[((size_t)p * KCLUS + k0 + cc) * 8];
        short* l = &dst[(size_t)e * 8];
        __builtin_amdgcn_global_load_lds(
            (const __attribute__((address_space(1))) unsigned int*)g,
            (__attribute__((address_space(3))) unsigned int*)l, 16, 0, 0);
    }
}

// ---------------------------------------------------------------------------
// Assign: r11 = r10-polish with PPW 32->64 (4 rt, halves per-point LDS-B reads
// and loop overhead) + async double-buffered global_load_lds staging (one
// __syncthreads per chunk; its vmcnt(0) drain lands AFTER compute, so next
// chunk's loads overlap the whole compute phase).  Per-(row,k) arithmetic is
// bit-identical to r9/r10: same A-frag bf16, same cbs_t B data, same fp32 cnv
// acc-init, same MFMA -> same capture set -> same exact refine -> absmax 0.
// ---------------------------------------------------------------------------
__global__ __launch_bounds__(256) void assign_kernel(
    const float* __restrict__ x, const float* __restrict__ c,
    const short* __restrict__ cbs_t, const float* __restrict__ cnorm,
    const float* __restrict__ cmaxp,
    float* __restrict__ out_assign, unsigned short* __restrict__ a16)
{
    __shared__ short csh[2][8 * CHUNKC * 8];   // 2 x 32 KB double buffer = 64 KB

    const int tid = threadIdx.x, wv = tid >> 6, lane = tid & 63;
    const int col = lane & 15, q = lane >> 4;
    const int pt0 = blockIdx.x * PPB + wv * PPW;

    // Kick chunk 0 staging immediately; it overlaps the A-frag build below.
    stage_chunk(cbs_t, &csh[0][0], 0, wv, lane);

    // A-frags (proven layout) + inline row norms (proven butterfly over lane
    // bits 16/32), extended to 4 row-tiles.
    frag_ab A[4][2];
    float nrm[4];
#pragma unroll
    for (int rt = 0; rt < 4; ++rt) {
        float ps = 0.f;
#pragma unroll
        for (int kh = 0; kh < 2; ++kh) {
            const float4* xp = (const float4*)&x[(size_t)(pt0 + rt * 16 + col) * FEAT + kh * 32 + q * 8];
            float4 v0 = xp[0], v1 = xp[1];
            frag_ab a;
            a[0] = f2bf(v0.x); a[1] = f2bf(v0.y); a[2] = f2bf(v0.z); a[3] = f2bf(v0.w);
            a[4] = f2bf(v1.x); a[5] = f2bf(v1.y); a[6] = f2bf(v1.z); a[7] = f2bf(v1.w);
            A[rt][kh] = a;
            ps = fmaf(v0.x, v0.x, ps); ps = fmaf(v0.y, v0.y, ps);
            ps = fmaf(v0.z, v0.z, ps); ps = fmaf(v0.w, v0.w, ps);
            ps = fmaf(v1.x, v1.x, ps); ps = fmaf(v1.y, v1.y, ps);
            ps = fmaf(v1.z, v1.z, ps); ps = fmaf(v1.w, v1.w, ps);
        }
        ps += __shfl_xor(ps, 16);
        ps += __shfl_xor(ps, 32);
        nrm[rt] = sqrtf(ps);
    }

    float m[4][4];
#pragma unroll
    for (int rt = 0; rt < 4; ++rt)
#pragma unroll
        for (int r = 0; r < 4; ++r) m[rt][r] = INFINITY;

    __syncthreads();   // chunk 0 staged (vmcnt(0) drain) for all waves

    // ------------------- PASS 1: approx min --------------------------------
    for (int c8 = 0; c8 < NCHUNK; ++c8) {
        const int cur = c8 & 1;
        // Issue next chunk into the other buffer; safe: that buffer was last
        // read in iter c8-1, sealed by that iter's trailing __syncthreads.
        stage_chunk(cbs_t, &csh[cur ^ 1][0], ((c8 + 1) & 7) * CHUNKC, wv, lane);
        const short* cbuf = &csh[cur][0];
        const int k0 = c8 * CHUNKC;
#pragma unroll 2
        for (int ct = 0; ct < CHUNKC / 16; ++ct) {
            const int lc = ct * 16 + col;
            frag_ab b0 = *(const frag_ab*)&cbuf[(q * CHUNKC + lc) * 8];
            frag_ab b1 = *(const frag_ab*)&cbuf[((4 + q) * CHUNKC + lc) * 8];
            const float cnv = cnorm[k0 + lc];   // 8 KB, L1/L2-resident; bit-identical
#pragma unroll
            for (int rt = 0; rt < 4; ++rt) {
                frag_cd acc = {cnv, cnv, cnv, cnv};
                acc = __builtin_amdgcn_mfma_f32_16x16x32_bf16(A[rt][0], b0, acc, 0, 0, 0);
                acc = __builtin_amdgcn_mfma_f32_16x16x32_bf16(A[rt][1], b1, acc, 0, 0, 0);
                m[rt][0] = fminf(m[rt][0], acc[0]);
                m[rt][1] = fminf(m[rt][1], acc[1]);
                m[rt][2] = fminf(m[rt][2], acc[2]);
                m[rt][3] = fminf(m[rt][3], acc[3]);
            }
        }
        // Drains next-chunk loads (they had the whole compute phase) + barrier.
        __syncthreads();
    }
    // NOTE: pass-1's last iteration staged chunk 0 back into buf0, drained by
    // its trailing __syncthreads -> pass 2 needs no prologue.

    // Threshold: m~ + 0.034*||x||*cmax >= m~ + 2*eps_bf16 (proven margin).
    const float cmax = *cmaxp;
    float t[4][4];
#pragma unroll
    for (int rt = 0; rt < 4; ++rt)
#pragma unroll
        for (int r = 0; r < 4; ++r) {
            float mm = m[rt][r];
            mm = fminf(mm, __shfl_xor(mm, 1));
            mm = fminf(mm, __shfl_xor(mm, 2));
            mm = fminf(mm, __shfl_xor(mm, 4));
            mm = fminf(mm, __shfl_xor(mm, 8));
            float xnp = __shfl(nrm[rt], q * 4 + r);   // lane q*4+r holds that row's norm
            t[rt][r] = mm + 0.034f * xnp * cmax;
        }

    // ------------------- PASS 2: per-lane register capture -----------------
    unsigned codes[CANDC];
    int ccnt = 0;

    for (int c8 = 0; c8 < NCHUNK; ++c8) {
        const int cur = c8 & 1;
        stage_chunk(cbs_t, &csh[cur ^ 1][0], ((c8 + 1) & 7) * CHUNKC, wv, lane);
        const short* cbuf = &csh[cur][0];
        const int k0 = c8 * CHUNKC;
#pragma unroll 2
        for (int ct = 0; ct < CHUNKC / 16; ++ct) {
            const int lc = ct * 16 + col;
            frag_ab b0 = *(const frag_ab*)&cbuf[(q * CHUNKC + lc) * 8];
            frag_ab b1 = *(const frag_ab*)&cbuf[((4 + q) * CHUNKC + lc) * 8];
            const float cnv = cnorm[k0 + lc];
            const int kk = k0 + lc;
#pragma unroll
            for (int rt = 0; rt < 4; ++rt) {
                frag_cd acc = {cnv, cnv, cnv, cnv};
                acc = __builtin_amdgcn_mfma_f32_16x16x32_bf16(A[rt][0], b0, acc, 0, 0, 0);
                acc = __builtin_amdgcn_mfma_f32_16x16x32_bf16(A[rt][1], b1, acc, 0, 0, 0);
#pragma unroll
                for (int r = 0; r < 4; ++r) {
                    if (acc[r] <= t[rt][r]) {   // rare
                        unsigned code = ((unsigned)(rt * 16 + q * 4 + r) << 11) | (unsigned)kk;
#pragma unroll
                        for (int s = 0; s < CANDC; ++s)   // register-file push
                            if (s == ccnt) codes[s] = code;
                        ccnt++;
                    }
                }
            }
        }
        __syncthreads();
    }

    // ------------------- exact refine (per-lane, registers) ----------------
    const bool anyovf = __any(ccnt > CANDC);

    if (!anyovf) {
        float bestd[4][4];
        int   bestk[4][4];
#pragma unroll
        for (int rt = 0; rt < 4; ++rt)
#pragma unroll
            for (int r = 0; r < 4; ++r) { bestd[rt][r] = INFINITY; bestk[rt][r] = 0x7fffffff; }

        for (int i = 0; i < CANDC; ++i) {
            if (i < ccnt) {
                unsigned code = codes[i];
                int pl = (int)(code >> 11), kk = (int)(code & 2047u);
                float e = exact_dist(x, c, cnorm[kk], pt0 + pl, kk);
                int crt = pl >> 4, cr = pl & 3;
#pragma unroll
                for (int rt = 0; rt < 4; ++rt)
#pragma unroll
                    for (int r = 0; r < 4; ++r)
                        if (crt == rt && cr == r &&
                            (e < bestd[rt][r] || (e == bestd[rt][r] && kk < bestk[rt][r]))) {
                            bestd[rt][r] = e; bestk[rt][r] = kk;
                        }
            }
        }

        // Proven cross-lane (d,k) reduce + col==0 writes (float4 + ushort4).
#pragma unroll
        for (int rt = 0; rt < 4; ++rt) {
#pragma unroll
            for (int r = 0; r < 4; ++r) {
                float bd = bestd[rt][r]; int bk = bestk[rt][r];
#pragma unroll
                for (int mask = 1; mask <= 8; mask <<= 1) {
                    float od = __shfl_xor(bd, mask);
                    int   ok = __shfl_xor(bk, mask);
                    if (od < bd || (od == bd && ok < bk)) { bd = od; bk = ok; }
                }
                bestd[rt][r] = bd; bestk[rt][r] = bk;
            }
            if (col == 0) {
                float4 w = { (float)bestk[rt][0], (float)bestk[rt][1],
                             (float)bestk[rt][2], (float)bestk[rt][3] };
                *(float4*)&out_assign[pt0 + rt * 16 + q * 4] = w;
                ushort4 u = { (unsigned short)bestk[rt][0], (unsigned short)bestk[rt][1],
                              (unsigned short)bestk[rt][2], (unsigned short)bestk[rt][3] };
                *(ushort4*)&a16[pt0 + rt * 16 + q * 4] = u;
            }
        }
    } else {
        // Overflow (rare): whole-wave fully-exact argmin, no thresholds.
        for (int pp = 0; pp < PPW; ++pp) {
            const int p = pt0 + pp;
            float bd = INFINITY; int bk = 0x7fffffff;
            for (int kk = lane; kk < KCLUS; kk += 64) {
                float e = exact_dist(x, c, cnorm[kk], p, kk);
                if (e < bd || (e == bd && kk < bk)) { bd = e; bk = kk; }
            }
#pragma unroll
            for (int mask = 1; mask <= 32; mask <<= 1) {
                float od = __shfl_xor(bd, mask);
                int   ok = __shfl_xor(bk, mask);
                if (od < bd || (od == bd && ok < bk)) { bd = od; bk = ok; }
            }
            if (lane == 0) {
                out_assign[p] = (float)bk;
                a16[p] = (unsigned short)bk;
            }
        }
    }
}

// ---------------------------------------------------------------------------
// Scatter (r10-proven, verbatim): block (cg, slice) owns clusters [8cg,8cg+8)
// over point slice [slice*16384, +16384). Ballot-collect, per-wave LDS
// accumulate, 8 atomic rows per block.
// ---------------------------------------------------------------------------
__global__ void scatter_kernel(const float* __restrict__ x,
                               const unsigned short* __restrict__ a16,
                               float* __restrict__ sums, int* __restrict__ counts) {
    __shared__ float wsum[4][8][64];   // 8 KB, per-wave private
    __shared__ int   wcnt[4][8];

    const int tid = threadIdx.x, wv = tid >> 6, lane = tid & 63;
    const int c0 = blockIdx.x * 8;

    for (int idx = tid; idx < 4 * 8 * 64; idx += 256) ((float*)wsum)[idx] = 0.f;
    if (tid < 32) ((int*)wcnt)[tid] = 0;
    __syncthreads();

    const int base = blockIdx.y * 16384 + wv * 4096;
#pragma unroll 1
    for (int it = 0; it < 64; ++it) {
        const int pbase = base + it * 64;
        int a = (int)a16[pbase + lane];                    // coalesced 128B
        unsigned long long mask = __ballot(a >= c0 && a < c0 + 8);
        while (mask) {
            int j = __ffsll((long long)mask) - 1;
            mask &= mask - 1;
            int cl = __shfl(a, j) - c0;
            float xv = x[(size_t)(pbase + j) * FEAT + lane];  // coalesced 256B row
            wsum[wv][cl][lane] += xv;                         // own slice: no race
            if (lane == 0) wcnt[wv][cl] += 1;
        }
    }
    __syncthreads();

    for (int idx = tid; idx < 512; idx += 256) {
        int cl = idx >> 6, ln = idx & 63;
        float s = wsum[0][cl][ln] + wsum[1][cl][ln] + wsum[2][cl][ln] + wsum[3][cl][ln];
        atomicAdd(&sums[(size_t)(c0 + cl) * FEAT + ln], s);
    }
    if (tid < 8) {
        int cc = wcnt[0][tid] + wcnt[1][tid] + wcnt[2][tid] + wcnt[3][tid];
        if (cc) atomicAdd(&counts[c0 + tid], cc);
    }
}

__global__ void update_kernel(const float* __restrict__ c,
                              const float* __restrict__ sums,
                              const int* __restrict__ counts,
                              float* __restrict__ out_upd) {
    int i = blockIdx.x * blockDim.x + threadIdx.x;
    if (i < KCLUS * FEAT) {
        int   k   = i >> 6;
        float cv  = c[i];
        int   cnt = counts[k];
        float nc  = (cnt > 0) ? (sums[i] / (float)cnt) : cv;
        out_upd[i] = 0.99f * cv + 0.01f * nc;
    }
}

extern "C" void kernel_launch(void* const* d_in, const int* in_sizes, int n_in,
                              void* d_out, int out_size, void* d_ws, size_t ws_size,
                              hipStream_t stream) {
    const float* x = (const float*)d_in[0];
    const float* c = (const float*)d_in[1];

    float* out        = (float*)d_out;
    float* out_assign = out;          // [0, N): assignments as float
    float* out_upd    = out + NPTS;   // [N, N + K*FEAT)

    // Workspace ~1.06 MB.
    char* ws = (char*)d_ws;
    constexpr size_t O_CNORM = 0;                       // 8 KB
    constexpr size_t O_CBS   = 8192;                    // 256 KB
    constexpr size_t O_ZERO  = 8192 + 262144;           // 270336
    constexpr size_t O_CMAX  = O_ZERO;                  // 64 B
    constexpr size_t O_SUMS  = O_ZERO + 64;             // 512 KB
    constexpr size_t O_CNTS  = O_SUMS + 524288;         // 8 KB
    constexpr size_t ZERO_LEN = 64 + 524288 + 8192;     // 532544
    constexpr size_t O_A16   = O_ZERO + ZERO_LEN;       // 802880, 256 KB

    float*    cnorm  = (float*)(ws + O_CNORM);
    short*    cbs_t  = (short*)(ws + O_CBS);
    float*    cmax   = (float*)(ws + O_CMAX);
    float*    sums   = (float*)(ws + O_SUMS);
    int*      counts = (int*)(ws + O_CNTS);
    unsigned short* a16 = (unsigned short*)(ws + O_A16);

    hipMemsetAsync(ws + O_ZERO, 0, ZERO_LEN, stream);

    cprep_kernel<<<KCLUS / 256, 256, 0, stream>>>(c, cnorm, cbs_t, cmax);
    // 4 waves/block x 64 pts/wave = 256 pts/block -> grid 512 (2 blocks/CU)
    assign_kernel<<<NPTS / PPB, 256, 0, stream>>>(x, c, cbs_t, cnorm, cmax,
                                                  out_assign, a16);
    scatter_kernel<<<dim3(KCLUS / 8, 8), 256, 0, stream>>>(x, a16, sums, counts);
    update_kernel<<<(KCLUS * FEAT) / 256, 256, 0, stream>>>(c, sums, counts, out_upd);
}

// Round 2
// 303.234 us; speedup vs baseline: 1.0142x; 1.0142x over previous
//
#include <hip/hip_runtime.h>
#include <math.h>

#define NPTS    131072
#define FEAT    64
#define KCLUS   2048
#define CHUNKC  128      // clusters staged per LDS chunk (dbuf: 2 x 16 KB)
#define NCHUNK  (KCLUS / CHUNKC)   // 16
#define PPW     32       // points per wave (2 MFMA row-tiles) -- r0 geometry
#define WPB     4        // waves per 256-thread block (wave = 64 on CDNA!)
#define PPB     (PPW * WPB)   // 128 points per block -> grid 1024 (4 blocks/CU)
#define CANDC   10       // per-lane register candidate slots (r0-proven)

typedef __attribute__((ext_vector_type(8))) short frag_ab;   // 8 bf16
typedef __attribute__((ext_vector_type(4))) float frag_cd;   // 4 fp32 acc

// fp32 -> bf16 RNE
__device__ __forceinline__ short f2bf(float f) {
    unsigned u = __float_as_uint(f);
    u += 0x7FFFu + ((u >> 16) & 1u);
    return (short)(u >> 16);
}

// Exact fp32 distance term (cn - 2 x.c): IDENTICAL single-chain FMA order to
// rounds 1-3/7/9/10 (matches numpy argmin on this data, absmax 0 x8).
__device__ __forceinline__ float exact_dist(const float* __restrict__ x,
                                            const float* __restrict__ c,
                                            float cnv, int p, int kk) {
    const float4* xr4 = (const float4*)&x[(size_t)p * FEAT];
    const float4* cr4 = (const float4*)&c[(size_t)kk * FEAT];
    float s = 0.f;
#pragma unroll
    for (int j = 0; j < 16; ++j) {
        float4 a4 = xr4[j], b4 = cr4[j];
        s = fmaf(a4.x, b4.x, s); s = fmaf(a4.y, b4.y, s);
        s = fmaf(a4.z, b4.z, s); s = fmaf(a4.w, b4.w, s);
    }
    return fmaf(-2.f, s, cnv);
}

// ---------------------------------------------------------------------------
// cprep: exact fp32 cnorm, cbs_t = bf16(-2c) part-major [part=f/8][k][8]
// (proven conflict-free + correct B layout), cmax = max||c||.  UNCHANGED.
// ---------------------------------------------------------------------------
__global__ void cprep_kernel(const float* __restrict__ c, float* __restrict__ cnorm,
                             short* __restrict__ cbs_t, float* __restrict__ cmax) {
    int k = blockIdx.x * blockDim.x + threadIdx.x;
    if (k >= KCLUS) return;
    const float4* row = (const float4*)&c[k * FEAT];
    float s = 0.f;
#pragma unroll
    for (int j = 0; j < 16; ++j) {
        float4 v = row[j];
        s = fmaf(v.x, v.x, s); s = fmaf(v.y, v.y, s);
        s = fmaf(v.z, v.z, s); s = fmaf(v.w, v.w, s);
        short4 b;
        b.x = f2bf(-2.f * v.x); b.y = f2bf(-2.f * v.y);
        b.z = f2bf(-2.f * v.z); b.w = f2bf(-2.f * v.w);
        *(short4*)&cbs_t[((size_t)(j >> 1) * KCLUS + k) * 8 + (j & 1) * 4] = b;
    }
    cnorm[k] = s;
    atomicMax((int*)cmax, __float_as_int(sqrtf(s)));  // positive: int-max == float-max
}

// ---------------------------------------------------------------------------
// Async-stage one 128-cluster chunk (16 KB B + 512 B cnorm) via
// global_load_lds: per wave 4 x 16B issues (entries e=(wv*4+j)*64+lane,
// part=e>>7, cc=e&127 -- byte-identical part-major layout to the proven csh),
// plus waves 0-1 stage cnorm (width 4).  LDS dest is wave-uniform base +
// lane*size (linear) as required; global src is per-lane.  No VGPR round
// trip, no ds_write traffic, no serial staging phase between barriers.
// ---------------------------------------------------------------------------
__device__ __forceinline__ void stage_chunk(const short* __restrict__ cbs_t,
                                            const float* __restrict__ cnorm,
                                            short* dstB, float* dstN,
                                            int k0, int wv, int lane) {
#pragma unroll
    for (int j = 0; j < 4; ++j) {
        const int e = (wv * 4 + j) * 64 + lane;        // [0, 1024)
        const int p = e >> 7, cc = e & 127;
        const short* g = &cbs_t[((size_t)p * KCLUS + k0 + cc) * 8];
        short* l = &dstB[(size_t)e * 8];
        __builtin_amdgcn_global_load_lds(
            (const __attribute__((address_space(1))) unsigned int*)g,
            (__attribute__((address_space(3))) unsigned int*)l, 16, 0, 0);
    }
    if (wv < 2) {   // wave-uniform branch
        const float* g = &cnorm[k0 + wv * 64 + lane];
        float* l = &dstN[wv * 64 + lane];
        __builtin_amdgcn_global_load_lds(
            (const __attribute__((address_space(1))) unsigned int*)g,
            (__attribute__((address_space(3))) unsigned int*)l, 4, 0, 0);
    }
}

// ---------------------------------------------------------------------------
// Assign: r0 geometry (PPW=32, grid 1024 -> occupancy headroom 16 waves/CU)
// + r1's proven async double-buffered global_load_lds staging (one barrier
// per chunk; its implicit vmcnt(0) drain lands AFTER the compute phase, so
// next-chunk loads overlap compute).  Per-(row,k) arithmetic, k-order,
// capture order and refine are bit-identical to r0 -> absmax 0.
// ---------------------------------------------------------------------------
__global__ __launch_bounds__(256) void assign_kernel(
    const float* __restrict__ x, const float* __restrict__ c,
    const short* __restrict__ cbs_t, const float* __restrict__ cnorm,
    const float* __restrict__ cmaxp,
    float* __restrict__ out_assign, unsigned short* __restrict__ a16)
{
    __shared__ short csh[2][8 * CHUNKC * 8];   // 2 x 16 KB double buffer
    __shared__ float cnsh[2][CHUNKC];          // 2 x 512 B

    const int tid = threadIdx.x, wv = tid >> 6, lane = tid & 63;
    const int col = lane & 15, q = lane >> 4;
    const int pt0 = blockIdx.x * PPB + wv * PPW;

    // Kick chunk 0 staging immediately; it overlaps the A-frag build below.
    stage_chunk(cbs_t, cnorm, &csh[0][0], &cnsh[0][0], 0, wv, lane);

    // A-frags (proven layout) + inline row norms (proven butterfly over lane
    // bits 16/32: lane's 16 feats of row rt*16+col -> full norm).
    frag_ab A[2][2];
    float nrm[2];
#pragma unroll
    for (int rt = 0; rt < 2; ++rt) {
        float ps = 0.f;
#pragma unroll
        for (int kh = 0; kh < 2; ++kh) {
            const float4* xp = (const float4*)&x[(size_t)(pt0 + rt * 16 + col) * FEAT + kh * 32 + q * 8];
            float4 v0 = xp[0], v1 = xp[1];
            frag_ab a;
            a[0] = f2bf(v0.x); a[1] = f2bf(v0.y); a[2] = f2bf(v0.z); a[3] = f2bf(v0.w);
            a[4] = f2bf(v1.x); a[5] = f2bf(v1.y); a[6] = f2bf(v1.z); a[7] = f2bf(v1.w);
            A[rt][kh] = a;
            ps = fmaf(v0.x, v0.x, ps); ps = fmaf(v0.y, v0.y, ps);
            ps = fmaf(v0.z, v0.z, ps); ps = fmaf(v0.w, v0.w, ps);
            ps = fmaf(v1.x, v1.x, ps); ps = fmaf(v1.y, v1.y, ps);
            ps = fmaf(v1.z, v1.z, ps); ps = fmaf(v1.w, v1.w, ps);
        }
        ps += __shfl_xor(ps, 16);
        ps += __shfl_xor(ps, 32);
        nrm[rt] = sqrtf(ps);
    }

    float m[2][4];
#pragma unroll
    for (int rt = 0; rt < 2; ++rt)
#pragma unroll
        for (int r = 0; r < 4; ++r) m[rt][r] = INFINITY;

    __syncthreads();   // chunk 0 staged (vmcnt(0) drain) for all waves

    // ------------------- PASS 1: approx min --------------------------------
    for (int c8 = 0; c8 < NCHUNK; ++c8) {
        const int cur = c8 & 1;
        // Issue next chunk into the other buffer; safe: that buffer was last
        // read in iter c8-1, sealed by that iter's trailing __syncthreads.
        stage_chunk(cbs_t, cnorm, &csh[cur ^ 1][0], &cnsh[cur ^ 1][0],
                    ((c8 + 1) & (NCHUNK - 1)) * CHUNKC, wv, lane);
        const short* cbuf = &csh[cur][0];
        const float* cnbuf = &cnsh[cur][0];
#pragma unroll 4
        for (int ct = 0; ct < CHUNKC / 16; ++ct) {
            const int lc = ct * 16 + col;
            frag_ab b0 = *(const frag_ab*)&cbuf[(q * CHUNKC + lc) * 8];
            frag_ab b1 = *(const frag_ab*)&cbuf[((4 + q) * CHUNKC + lc) * 8];
            const float cnv = cnbuf[lc];
#pragma unroll
            for (int rt = 0; rt < 2; ++rt) {
                frag_cd acc = {cnv, cnv, cnv, cnv};
                acc = __builtin_amdgcn_mfma_f32_16x16x32_bf16(A[rt][0], b0, acc, 0, 0, 0);
                acc = __builtin_amdgcn_mfma_f32_16x16x32_bf16(A[rt][1], b1, acc, 0, 0, 0);
                m[rt][0] = fminf(m[rt][0], acc[0]);
                m[rt][1] = fminf(m[rt][1], acc[1]);
                m[rt][2] = fminf(m[rt][2], acc[2]);
                m[rt][3] = fminf(m[rt][3], acc[3]);
            }
        }
        // Drains next-chunk loads (they had the whole compute phase) + barrier.
        __syncthreads();
    }
    // Pass-1's last iteration staged chunk 0 back into buf0, drained by its
    // trailing __syncthreads -> pass 2 needs no prologue.

    // Threshold: m~ + 0.034*||x||*cmax >= m~ + 2*eps_bf16 (proven margin).
    const float cmax = *cmaxp;
    float t[2][4];
#pragma unroll
    for (int rt = 0; rt < 2; ++rt)
#pragma unroll
        for (int r = 0; r < 4; ++r) {
            float mm = m[rt][r];
            mm = fminf(mm, __shfl_xor(mm, 1));
            mm = fminf(mm, __shfl_xor(mm, 2));
            mm = fminf(mm, __shfl_xor(mm, 4));
            mm = fminf(mm, __shfl_xor(mm, 8));
            float xnp = __shfl(nrm[rt], q * 4 + r);   // lane q*4+r holds that row's norm
            t[rt][r] = mm + 0.034f * xnp * cmax;
        }

    // ------------------- PASS 2: per-lane register capture -----------------
    unsigned codes[CANDC];
    int ccnt = 0;

    for (int c8 = 0; c8 < NCHUNK; ++c8) {
        const int cur = c8 & 1;
        stage_chunk(cbs_t, cnorm, &csh[cur ^ 1][0], &cnsh[cur ^ 1][0],
                    ((c8 + 1) & (NCHUNK - 1)) * CHUNKC, wv, lane);
        const short* cbuf = &csh[cur][0];
        const float* cnbuf = &cnsh[cur][0];
        const int k0 = c8 * CHUNKC;
#pragma unroll 2
        for (int ct = 0; ct < CHUNKC / 16; ++ct) {
            const int lc = ct * 16 + col;
            frag_ab b0 = *(const frag_ab*)&cbuf[(q * CHUNKC + lc) * 8];
            frag_ab b1 = *(const frag_ab*)&cbuf[((4 + q) * CHUNKC + lc) * 8];
            const float cnv = cnbuf[lc];
            const int kk = k0 + lc;
#pragma unroll
            for (int rt = 0; rt < 2; ++rt) {
                frag_cd acc = {cnv, cnv, cnv, cnv};
                acc = __builtin_amdgcn_mfma_f32_16x16x32_bf16(A[rt][0], b0, acc, 0, 0, 0);
                acc = __builtin_amdgcn_mfma_f32_16x16x32_bf16(A[rt][1], b1, acc, 0, 0, 0);
#pragma unroll
                for (int r = 0; r < 4; ++r) {
                    if (acc[r] <= t[rt][r]) {   // rare
                        unsigned code = ((unsigned)(rt * 16 + q * 4 + r) << 11) | (unsigned)kk;
#pragma unroll
                        for (int s = 0; s < CANDC; ++s)   // register-file push
                            if (s == ccnt) codes[s] = code;
                        ccnt++;
                    }
                }
            }
        }
        __syncthreads();
    }

    // ------------------- exact refine (per-lane, registers) ----------------
    const bool anyovf = __any(ccnt > CANDC);

    if (!anyovf) {
        float bestd[2][4];
        int   bestk[2][4];
#pragma unroll
        for (int rt = 0; rt < 2; ++rt)
#pragma unroll
            for (int r = 0; r < 4; ++r) { bestd[rt][r] = INFINITY; bestk[rt][r] = 0x7fffffff; }

        for (int i = 0; i < CANDC; ++i) {
            if (i < ccnt) {
                unsigned code = codes[i];
                int pl = (int)(code >> 11), kk = (int)(code & 2047u);
                float e = exact_dist(x, c, cnorm[kk], pt0 + pl, kk);
                int crt = pl >> 4, cr = pl & 3;
#pragma unroll
                for (int rt = 0; rt < 2; ++rt)
#pragma unroll
                    for (int r = 0; r < 4; ++r)
                        if (crt == rt && cr == r &&
                            (e < bestd[rt][r] || (e == bestd[rt][r] && kk < bestk[rt][r]))) {
                            bestd[rt][r] = e; bestk[rt][r] = kk;
                        }
            }
        }

        // Proven cross-lane (d,k) reduce + col==0 writes (float4 + ushort4).
#pragma unroll
        for (int rt = 0; rt < 2; ++rt) {
#pragma unroll
            for (int r = 0; r < 4; ++r) {
                float bd = bestd[rt][r]; int bk = bestk[rt][r];
#pragma unroll
                for (int mask = 1; mask <= 8; mask <<= 1) {
                    float od = __shfl_xor(bd, mask);
                    int   ok = __shfl_xor(bk, mask);
                    if (od < bd || (od == bd && ok < bk)) { bd = od; bk = ok; }
                }
                bestd[rt][r] = bd; bestk[rt][r] = bk;
            }
            if (col == 0) {
                float4 w = { (float)bestk[rt][0], (float)bestk[rt][1],
                             (float)bestk[rt][2], (float)bestk[rt][3] };
                *(float4*)&out_assign[pt0 + rt * 16 + q * 4] = w;
                ushort4 u = { (unsigned short)bestk[rt][0], (unsigned short)bestk[rt][1],
                              (unsigned short)bestk[rt][2], (unsigned short)bestk[rt][3] };
                *(ushort4*)&a16[pt0 + rt * 16 + q * 4] = u;
            }
        }
    } else {
        // Overflow (rare): whole-wave fully-exact argmin, no thresholds.
        for (int pp = 0; pp < PPW; ++pp) {
            const int p = pt0 + pp;
            float bd = INFINITY; int bk = 0x7fffffff;
            for (int kk = lane; kk < KCLUS; kk += 64) {
                float e = exact_dist(x, c, cnorm[kk], p, kk);
                if (e < bd || (e == bd && kk < bk)) { bd = e; bk = kk; }
            }
#pragma unroll
            for (int mask = 1; mask <= 32; mask <<= 1) {
                float od = __shfl_xor(bd, mask);
                int   ok = __shfl_xor(bk, mask);
                if (od < bd || (od == bd && ok < bk)) { bd = od; bk = ok; }
            }
            if (lane == 0) {
                out_assign[p] = (float)bk;
                a16[p] = (unsigned short)bk;
            }
        }
    }
}

// ---------------------------------------------------------------------------
// Scatter (r10-proven, verbatim): block (cg, slice) owns clusters [8cg,8cg+8)
// over point slice [slice*16384, +16384). Ballot-collect, per-wave LDS
// accumulate, 8 atomic rows per block.
// ---------------------------------------------------------------------------
__global__ void scatter_kernel(const float* __restrict__ x,
                               const unsigned short* __restrict__ a16,
                               float* __restrict__ sums, int* __restrict__ counts) {
    __shared__ float wsum[4][8][64];   // 8 KB, per-wave private
    __shared__ int   wcnt[4][8];

    const int tid = threadIdx.x, wv = tid >> 6, lane = tid & 63;
    const int c0 = blockIdx.x * 8;

    for (int idx = tid; idx < 4 * 8 * 64; idx += 256) ((float*)wsum)[idx] = 0.f;
    if (tid < 32) ((int*)wcnt)[tid] = 0;
    __syncthreads();

    const int base = blockIdx.y * 16384 + wv * 4096;
#pragma unroll 1
    for (int it = 0; it < 64; ++it) {
        const int pbase = base + it * 64;
        int a = (int)a16[pbase + lane];                    // coalesced 128B
        unsigned long long mask = __ballot(a >= c0 && a < c0 + 8);
        while (mask) {
            int j = __ffsll((long long)mask) - 1;
            mask &= mask - 1;
            int cl = __shfl(a, j) - c0;
            float xv = x[(size_t)(pbase + j) * FEAT + lane];  // coalesced 256B row
            wsum[wv][cl][lane] += xv;                         // own slice: no race
            if (lane == 0) wcnt[wv][cl] += 1;
        }
    }
    __syncthreads();

    for (int idx = tid; idx < 512; idx += 256) {
        int cl = idx >> 6, ln = idx & 63;
        float s = wsum[0][cl][ln] + wsum[1][cl][ln] + wsum[2][cl][ln] + wsum[3][cl][ln];
        atomicAdd(&sums[(size_t)(c0 + cl) * FEAT + ln], s);
    }
    if (tid < 8) {
        int cc = wcnt[0][tid] + wcnt[1][tid] + wcnt[2][tid] + wcnt[3][tid];
        if (cc) atomicAdd(&counts[c0 + tid], cc);
    }
}

__global__ void update_kernel(const float* __restrict__ c,
                              const float* __restrict__ sums,
                              const int* __restrict__ counts,
                              float* __restrict__ out_upd) {
    int i = blockIdx.x * blockDim.x + threadIdx.x;
    if (i < KCLUS * FEAT) {
        int   k   = i >> 6;
        float cv  = c[i];
        int   cnt = counts[k];
        float nc  = (cnt > 0) ? (sums[i] / (float)cnt) : cv;
        out_upd[i] = 0.99f * cv + 0.01f * nc;
    }
}

extern "C" void kernel_launch(void* const* d_in, const int* in_sizes, int n_in,
                              void* d_out, int out_size, void* d_ws, size_t ws_size,
                              hipStream_t stream) {
    const float* x = (const float*)d_in[0];
    const float* c = (const float*)d_in[1];

    float* out        = (float*)d_out;
    float* out_assign = out;          // [0, N): assignments as float
    float* out_upd    = out + NPTS;   // [N, N + K*FEAT)

    // Workspace ~1.06 MB.
    char* ws = (char*)d_ws;
    constexpr size_t O_CNORM = 0;                       // 8 KB
    constexpr size_t O_CBS   = 8192;                    // 256 KB
    constexpr size_t O_ZERO  = 8192 + 262144;           // 270336
    constexpr size_t O_CMAX  = O_ZERO;                  // 64 B
    constexpr size_t O_SUMS  = O_ZERO + 64;             // 512 KB
    constexpr size_t O_CNTS  = O_SUMS + 524288;         // 8 KB
    constexpr size_t ZERO_LEN = 64 + 524288 + 8192;     // 532544
    constexpr size_t O_A16   = O_ZERO + ZERO_LEN;       // 802880, 256 KB

    float*    cnorm  = (float*)(ws + O_CNORM);
    short*    cbs_t  = (short*)(ws + O_CBS);
    float*    cmax   = (float*)(ws + O_CMAX);
    float*    sums   = (float*)(ws + O_SUMS);
    int*      counts = (int*)(ws + O_CNTS);
    unsigned short* a16 = (unsigned short*)(ws + O_A16);

    hipMemsetAsync(ws + O_ZERO, 0, ZERO_LEN, stream);

    cprep_kernel<<<KCLUS / 256, 256, 0, stream>>>(c, cnorm, cbs_t, cmax);
    // 4 waves/block x 32 pts/wave = 128 pts/block -> grid 1024 (4 blocks/CU)
    assign_kernel<<<NPTS / PPB, 256, 0, stream>>>(x, c, cbs_t, cnorm, cmax,
                                                  out_assign, a16);
    scatter_kernel<<<dim3(KCLUS / 8, 8), 256, 0, stream>>>(x, a16, sums, counts);
    update_kernel<<<(KCLUS * FEAT) / 256, 256, 0, stream>>>(c, sums, counts, out_upd);
}